// Round 7
// baseline (57.565 us; speedup 1.0000x reference)
//
#include <hip/hip_runtime.h>
#include <hip/hip_bf16.h>
#include <string.h>

typedef __attribute__((ext_vector_type(8))) short bf16x8;
typedef __attribute__((ext_vector_type(4))) float f32x4;

namespace {
constexpr int B = 8, H = 128, W = 128, C = 128;
constexpr int MO = 9, NOFF = 81;
constexpr int ROWS = 8;          // output rows per block (1 per wave)
constexpr int WCOLS = 16;        // output cols per block
constexpr int F2R = 16;          // staged F2 rows (8 + 2*4 halo)
constexpr int F2S = 24;          // F2 col pitch == real cols
constexpr int SREAL = 24;        // fx = wb0-4 .. wb0+19
constexpr int CK = 32;           // channels per chunk (one MFMA K)
constexpr int NCH = C / CK;      // 4
constexpr int NT = 512;          // 8 waves
constexpr int NLD = 6;           // 16*24*8/512 staging float4 per thread
constexpr int RSTR = F2S * CK;   // 768 shorts per staged F2 row
constexpr int F2BUF = F2R * RSTR;// 12288 shorts per buffer
}

__device__ inline unsigned bf2pack(float a, float b) {
  // RTNE fp32->bf16 pair via v_cvt_pk_bf16_f32 (a = low half)
  __hip_bfloat162 h = __float22bfloat162_rn(float2{a, b});
  unsigned r;
  memcpy(&r, &h, sizeof(r));
  return r;
}

__device__ __forceinline__ f32x4 mfma16(bf16x8 a, bf16x8 b, f32x4 c) {
  return __builtin_amdgcn_mfma_f32_16x16x32_bf16(a, b, c, 0, 0, 0);
}

__global__ __launch_bounds__(NT, 3) void costvol_kernel(
    const float* __restrict__ F1, const float* __restrict__ F2,
    float* __restrict__ out)
{
  // +512 shorts pad: wave r=7, dy=8 t=1 reads spill past row 15 into pad;
  // those band entries are discarded in the epilogue (r6-verified safe).
  __shared__ __align__(16) short sF2[2 * F2BUF + 512];  // 50.2 KB

  const int lin  = blockIdx.x;
  const int b    = lin & 7;            // one batch per XCD
  const int tile = lin >> 3;           // 0..127
  const int rt   = tile & 15;          // rt fastest: halo rows reuse in L2
  const int wt   = tile >> 4;          // 0..7
  const int h0   = rt * ROWS;
  const int wb0  = wt * WCOLS;

  const int tid  = threadIdx.x;
  const int r    = tid >> 6;           // wave index = output row in tile
  const int lane = tid & 63;
  const int j    = lane & 15;          // MFMA m/n index
  const int kq   = lane >> 4;          // k-quarter

  // ---- loop-invariant F2 staging decode (OOB -> offset 0, zero at pack)
  int gofs[NLD]; int lofs[NLD]; unsigned okm = 0;
#pragma unroll
  for (int it = 0; it < NLD; ++it) {
    const int idx  = tid + it * NT;     // 0..3071
    const int kg   = idx & 7;
    const int slot = idx >> 3;          // 0..383
    const int ry   = slot / SREAL;
    const int s    = slot - ry * SREAL;
    const int fy   = h0 - 4 + ry;
    const int fx   = wb0 - 4 + s;
    const bool ok  = ((unsigned)fy < (unsigned)H) && ((unsigned)fx < (unsigned)W);
    okm |= (unsigned)ok << it;
    gofs[it] = ok ? (((b * H + fy) * W + fx) * C + kg * 4) : 0;
    lofs[it] = (ry * F2S + s) * CK + kg * 4;
  }

  auto issue = [&](int ch, float4* ld) {
#pragma unroll
    for (int it = 0; it < NLD; ++it) {
      ld[it] = *reinterpret_cast<const float4*>(F2 + gofs[it] + ch * CK);
    }
    __builtin_amdgcn_sched_barrier(0);  // loads must issue here, not sink
  };
  auto pack = [&](int buf, const float4* ld) {
#pragma unroll
    for (int it = 0; it < NLD; ++it) {
      if ((okm >> it) & 1u) {
        uint2 p;
        p.x = bf2pack(ld[it].x, ld[it].y);
        p.y = bf2pack(ld[it].z, ld[it].w);
        *reinterpret_cast<uint2*>(&sF2[buf * F2BUF + lofs[it]]) = p;
      }
    }
  };

  f32x4 acc[9][2];
#pragma unroll
  for (int d = 0; d < 9; ++d) { acc[d][0] = {0,0,0,0}; acc[d][1] = {0,0,0,0}; }

  auto compute = [&](int buf, bf16x8 af) {
    const short* bbase = &sF2[buf * F2BUF + j * CK + kq * 8];
#pragma unroll
    for (int dy = 0; dy < 9; ++dy) {
      const int ry = r + dy;
      const bf16x8 b0 = *reinterpret_cast<const bf16x8*>(bbase + ry * RSTR);
      const bf16x8 b1 = *reinterpret_cast<const bf16x8*>(bbase + ry * RSTR + 16 * CK);
      acc[dy][0] = mfma16(af, b0, acc[dy][0]);
      acc[dy][1] = mfma16(af, b1, acc[dy][1]);
    }
  };

  // ---- prologue: depth-2 issue (c0, c1); F1 direct->regs; pack c0; barrier
  bf16x8 a[NCH];
  float4 ldA[NLD], ldB[NLD];
  issue(0, ldA);
  issue(1, ldB);
  {
    const float* f1p = F1 + (((size_t)b * H + h0 + r) * W + wb0 + j) * C + kq * 8;
    float4 u0[NCH], u1[NCH];
#pragma unroll
    for (int ch = 0; ch < NCH; ++ch) {
      u0[ch] = *reinterpret_cast<const float4*>(f1p + ch * CK);
      u1[ch] = *reinterpret_cast<const float4*>(f1p + ch * CK + 4);
    }
    // zero OOB slots of BOTH buffers once (pack skips them thereafter)
#pragma unroll
    for (int it = 0; it < NLD; ++it) {
      if (!((okm >> it) & 1u)) {
        *reinterpret_cast<uint2*>(&sF2[lofs[it]]) = uint2{0u, 0u};
        *reinterpret_cast<uint2*>(&sF2[F2BUF + lofs[it]]) = uint2{0u, 0u};
      }
    }
    pack(0, ldA);
#pragma unroll
    for (int ch = 0; ch < NCH; ++ch) {
      uint4 q;
      q.x = bf2pack(u0[ch].x, u0[ch].y);
      q.y = bf2pack(u0[ch].z, u0[ch].w);
      q.z = bf2pack(u1[ch].x, u1[ch].y);
      q.w = bf2pack(u1[ch].z, u1[ch].w);
      a[ch] = __builtin_bit_cast(bf16x8, q);
    }
    __syncthreads();
  }

  // ---- depth-2 pipelined K loop (manually unrolled; ldA/ldB rotate)
  // c=0: compute buf0; c1 already in ldB; issue c2 into ldA
  issue(2, ldA);
  compute(0, a[0]);
  __builtin_amdgcn_sched_barrier(0);
  pack(1, ldB);
  __syncthreads();
  // c=1
  issue(3, ldB);
  compute(1, a[1]);
  __builtin_amdgcn_sched_barrier(0);
  pack(0, ldA);
  __syncthreads();
  // c=2
  compute(0, a[2]);
  __builtin_amdgcn_sched_barrier(0);
  pack(1, ldB);
  __syncthreads();
  // c=3
  compute(1, a[3]);

  // ---- epilogue: band extract, /128, leaky_relu(0.1), store
  // D layout: n = j (staged col s = j+16t), m = kq*4+reg (pixel i); dxi = s-i
  const int h = h0 + r;
  float* outb = out + (((size_t)b * H + h) * W + wb0) * NOFF;
#pragma unroll
  for (int dy = 0; dy < 9; ++dy) {
#pragma unroll
    for (int t = 0; t < 2; ++t) {
#pragma unroll
      for (int reg = 0; reg < 4; ++reg) {
        const int i   = kq * 4 + reg;
        const int dxi = j + t * 16 - i;
        if (dxi >= 0 && dxi <= 8) {
          float m = acc[dy][t][reg] * 0.0078125f;
          m = fmaxf(m, 0.1f * m);  // leaky_relu(0.1)
          outb[(size_t)i * NOFF + dy * MO + dxi] = m;
        }
      }
    }
  }
}

extern "C" void kernel_launch(void* const* d_in, const int* in_sizes, int n_in,
                              void* d_out, int out_size, void* d_ws, size_t ws_size,
                              hipStream_t stream) {
  const float* F1 = (const float*)d_in[0];
  const float* F2 = (const float*)d_in[1];
  float* out = (float*)d_out;
  dim3 grid(B * (H / ROWS) * (W / WCOLS));  // 8 * 16 * 8 = 1024 blocks
  dim3 block(NT);                           // 512 threads = 8 waves
  hipLaunchKernelGGL(costvol_kernel, grid, block, 0, stream, F1, F2, out);
}

// Round 8
// 43.270 us; speedup vs baseline: 1.3304x; 1.3304x over previous
//
#include <hip/hip_runtime.h>
#include <hip/hip_bf16.h>
#include <string.h>

typedef __attribute__((ext_vector_type(8))) short bf16x8;
typedef __attribute__((ext_vector_type(4))) float f32x4;

namespace {
constexpr int B = 8, H = 128, W = 128, C = 128;
constexpr int MO = 9, NOFF = 81;
constexpr int ROWS = 4;            // output rows per block (1 per wave)
constexpr int WCOLS = 16;          // output cols per block
constexpr int F2R = 12;            // staged F2 rows (4 + 2*4 halo)
constexpr int SREAL = 24;          // staged cols, fx = wb0-4 .. wb0+19
constexpr int NT = 256;            // 4 waves (must stay 4: reg cap ~12 waves/CU)
constexpr int NLD = 9;             // float4 loads per thread per k-slab
constexpr int KSTR = SREAL * 32;   // 768 shorts per k-slab (32 ch)
constexpr int ROWSTR = 4 * KSTR;   // 3072 shorts per staged row (128 ch)
constexpr int PADS = 256;          // tail pad: b1 spill of (ry=11,kk=3) lands here
}

__device__ inline unsigned bf2pack(float a, float b) {
  // RTNE fp32->bf16 pair via v_cvt_pk_bf16_f32 (a = low half)
  __hip_bfloat162 h = __float22bfloat162_rn(float2{a, b});
  unsigned r;
  memcpy(&r, &h, sizeof(r));
  return r;
}

__device__ __forceinline__ f32x4 mfma16(bf16x8 a, bf16x8 b, f32x4 c) {
  return __builtin_amdgcn_mfma_f32_16x16x32_bf16(a, b, c, 0, 0, 0);
}

__global__ __launch_bounds__(NT, 2) void costvol_kernel(
    const float* __restrict__ F1, const float* __restrict__ F2,
    float* __restrict__ out)
{
  // Single buffer, whole 128-ch tile: [ry][kk][s][32ch] bf16 = 74,240 B.
  // Each kk-slab has the r5-verified conflict-free banking.
  __shared__ __align__(16) short sF2[F2R * ROWSTR + PADS];

  const int lin  = blockIdx.x;
  const int b    = lin & 7;          // one batch per XCD
  const int tile = lin >> 3;         // 0..255
  const int rt   = tile & 31;        // rt fastest: halo rows reuse in L2
  const int wt   = tile >> 5;        // 0..7
  const int h0   = rt * ROWS;
  const int wb0  = wt * WCOLS;

  const int tid  = threadIdx.x;
  const int r    = tid >> 6;         // wave index = output row in tile
  const int lane = tid & 63;
  const int j    = lane & 15;        // MFMA m/n index
  const int kq   = lane >> 4;        // k-quarter within a slab

  // ---- loop-invariant staging decode (OOB -> offset 0, skipped at pack)
  int gofs[NLD]; int lofs[NLD]; unsigned okm = 0;
#pragma unroll
  for (int it = 0; it < NLD; ++it) {
    const int idx  = tid + it * NT;   // 0..2303
    const int kg   = idx & 7;         // channel-quad within slab
    const int slot = idx >> 3;        // 0..287 -> (ry, s)
    const int ry   = slot / SREAL;
    const int s    = slot - ry * SREAL;
    const int fy   = h0 - 4 + ry;
    const int fx   = wb0 - 4 + s;
    const bool ok  = ((unsigned)fy < (unsigned)H) && ((unsigned)fx < (unsigned)W);
    okm |= (unsigned)ok << it;
    gofs[it] = ok ? (((b * H + fy) * W + fx) * C + kg * 4) : 0;
    lofs[it] = ry * ROWSTR + s * 32 + kg * 4;
  }

  auto issue = [&](int g, float4* ld) {
#pragma unroll
    for (int it = 0; it < NLD; ++it) {
      ld[it] = *reinterpret_cast<const float4*>(F2 + gofs[it] + g * 32);
    }
    __builtin_amdgcn_sched_barrier(0);  // loads must issue here, not sink
  };
  auto pack = [&](int g, const float4* ld) {
#pragma unroll
    for (int it = 0; it < NLD; ++it) {
      if ((okm >> it) & 1u) {
        uint2 p;
        p.x = bf2pack(ld[it].x, ld[it].y);
        p.y = bf2pack(ld[it].z, ld[it].w);
        *reinterpret_cast<uint2*>(&sF2[lofs[it] + g * KSTR]) = p;
      }
    }
  };

  // ---- rolling staging pipeline: 2 groups in flight, 4 slabs total
  float4 ldA[NLD], ldB[NLD];
  issue(0, ldA);
  issue(1, ldB);
  // zero OOB slots (all 4 slabs) while g0 is in flight
#pragma unroll
  for (int it = 0; it < NLD; ++it) {
    if (!((okm >> it) & 1u)) {
#pragma unroll
      for (int g = 0; g < 4; ++g) {
        *reinterpret_cast<uint2*>(&sF2[lofs[it] + g * KSTR]) = uint2{0u, 0u};
      }
    }
  }
  pack(0, ldA);
  issue(2, ldA);
  pack(1, ldB);
  issue(3, ldB);
  pack(2, ldA);

  // F1 fragments direct from global (consumed after pack(3))
  const float* f1p = F1 + (((size_t)b * H + h0 + r) * W + wb0 + j) * C + kq * 8;
  float4 u0[4], u1[4];
#pragma unroll
  for (int kk = 0; kk < 4; ++kk) {
    u0[kk] = *reinterpret_cast<const float4*>(f1p + kk * 32);
    u1[kk] = *reinterpret_cast<const float4*>(f1p + kk * 32 + 4);
  }
  __builtin_amdgcn_sched_barrier(0);
  pack(3, ldB);

  // afrag with 1/128 prescale (exact exponent shift; epilogue mul removed)
  bf16x8 afrag[4];
  constexpr float S = 0.0078125f;
#pragma unroll
  for (int kk = 0; kk < 4; ++kk) {
    uint4 q;
    q.x = bf2pack(u0[kk].x * S, u0[kk].y * S);
    q.y = bf2pack(u0[kk].z * S, u0[kk].w * S);
    q.z = bf2pack(u1[kk].x * S, u1[kk].y * S);
    q.w = bf2pack(u1[kk].z * S, u1[kk].w * S);
    afrag[kk] = __builtin_bit_cast(bf16x8, q);
  }

  __syncthreads();  // the ONLY barrier

  // ---- compute burst: 72 ds_read_b128 + 72 MFMA
  f32x4 acc[9][2];
#pragma unroll
  for (int d = 0; d < 9; ++d) { acc[d][0] = {0,0,0,0}; acc[d][1] = {0,0,0,0}; }

  const short* bb = sF2 + j * 32 + kq * 8;
  __builtin_amdgcn_s_setprio(1);
#pragma unroll
  for (int kk = 0; kk < 4; ++kk) {
    const short* bk = bb + kk * KSTR;
#pragma unroll
    for (int dy = 0; dy < 9; ++dy) {
      const short* brow = bk + (r + dy) * ROWSTR;
      const bf16x8 b0 = *reinterpret_cast<const bf16x8*>(brow);
      const bf16x8 b1 = *reinterpret_cast<const bf16x8*>(brow + 512);
      acc[dy][0] = mfma16(afrag[kk], b0, acc[dy][0]);
      acc[dy][1] = mfma16(afrag[kk], b1, acc[dy][1]);
    }
  }
  __builtin_amdgcn_s_setprio(0);

  // ---- epilogue: band extract, leaky_relu(0.1), store
  // out idx = i*81 + dy*9 + dxi, i = kq*4+reg, dxi = j+16t-i
  //         = [lane: kq*320 + j] + [const: reg*80 + 16t + dy*9]
  const int h = h0 + r;
  float* lb = out + (((size_t)b * H + h) * W + wb0) * NOFF + kq * 320 + j;
#pragma unroll
  for (int t = 0; t < 2; ++t) {
#pragma unroll
    for (int reg = 0; reg < 4; ++reg) {
      const int dxl = j + 16 * t - kq * 4 - reg;  // lane-dependent dxi
      if ((unsigned)dxl <= 8u) {
#pragma unroll
        for (int dy = 0; dy < 9; ++dy) {
          float m = acc[dy][t][reg];               // already /128 via prescale
          m = fmaxf(m, 0.1f * m);                  // leaky_relu(0.1)
          lb[reg * 80 + 16 * t + dy * 9] = m;      // const offset folds to imm
        }
      }
    }
  }
}

extern "C" void kernel_launch(void* const* d_in, const int* in_sizes, int n_in,
                              void* d_out, int out_size, void* d_ws, size_t ws_size,
                              hipStream_t stream) {
  const float* F1 = (const float*)d_in[0];
  const float* F2 = (const float*)d_in[1];
  float* out = (float*)d_out;
  dim3 grid(B * (H / ROWS) * (W / WCOLS));  // 8 * 32 * 8 = 2048 blocks
  dim3 block(NT);                           // 256 threads = 4 waves
  hipLaunchKernelGGL(costvol_kernel, grid, block, 0, stream, F1, F2, out);
}